// Round 19
// baseline (331.407 us; speedup 1.0000x reference)
//
#include <hip/hip_runtime.h>
#include <hip/hip_bf16.h>
#include <stdint.h>

#define DI __device__ __forceinline__

namespace {

constexpr int BB  = 256;   // batch
constexpr int LL  = 128;   // seq len
constexpr int DM  = 64;    // d_model
constexpr int DFF = 512;   // ffn dim
constexpr int NL  = 6;     // layers
constexpr int TT  = BB * LL;  // 32768 tokens

typedef __attribute__((ext_vector_type(8))) short bf16x8;   // MFMA A/B frag (4 VGPR)
typedef __attribute__((ext_vector_type(4))) float f32x4;    // MFMA C/D frag

// ---------- bf16 helpers ----------
DI float bf2f(uint16_t u) { union { uint32_t i; float f; } w; w.i = (uint32_t)u << 16; return w.f; }
DI uint16_t f2bf(float f) {
  union { float f; uint32_t i; } w; w.f = f;
  uint32_t r = (w.i + 0x7fffu + ((w.i >> 16) & 1u)) >> 16;  // RNE
  return (uint16_t)r;
}
DI uint32_t pack2(float a, float b) { return (uint32_t)f2bf(a) | ((uint32_t)f2bf(b) << 16); }

// fragment load: lane l reads 8 bf16 at row (l&15), k-offset (l>>4)*8 of a row-major [16 x ld] tile
DI bf16x8 fragld(const uint16_t* __restrict__ base, int ld, int lane) {
  return *(const bf16x8*)(base + (size_t)(lane & 15) * ld + (lane >> 4) * 8);
}
DI f32x4 MFMA(bf16x8 a, bf16x8 b, f32x4 c) {
  return __builtin_amdgcn_mfma_f32_16x16x32_bf16(a, b, c, 0, 0, 0);
}

// ---------- setup kernels ----------
__global__ void __launch_bounds__(256) k_embed(const int* __restrict__ enc, const int* __restrict__ deg,
    const float* __restrict__ semb, const float* __restrict__ demb,
    float* __restrict__ x, uint16_t* __restrict__ xb) {
  int idx = blockIdx.x * 256 + threadIdx.x;   // T*64
  int t = idx >> 6, d = idx & 63;
  int l = t & (LL - 1);
  float e = (float)(d & ~1) * -0.14391156831212787f;   // -ln(10000)/64
  float ang = (float)l * __expf(e);
  float pe = (d & 1) ? __cosf(ang) : __sinf(ang);
  float v = semb[enc[t] * DM + d] + demb[deg[t] * DM + d] + pe;
  x[idx] = v;
  xb[idx] = f2bf(v);
}

__global__ void __launch_bounds__(256) k_trans(const float* __restrict__ w, uint16_t* __restrict__ wt,
    int K, int O, int dstStride, int colOff) {
  int idx = blockIdx.x * 256 + threadIdx.x;   // nmat*K*O
  int KO = K * O;
  int mat = idx / KO;
  int rem = idx - mat * KO;
  int c = rem / K;
  int k = rem - c * K;
  wt[(size_t)mat * dstStride + (size_t)(colOff + c) * K + k] = f2bf(w[((size_t)mat * K + k) * O + c]);
}

// biasT[b][h][r][kk] bf16 = mask(kk) ? -1e9 : md_emb[MD[b,r,kk]][h]   (layer-invariant)
__global__ void __launch_bounds__(256) k_bias2(const int* __restrict__ MD, const float* __restrict__ memb,
    const int* __restrict__ enc, uint16_t* __restrict__ biasT) {
  int o = blockIdx.x * 256 + threadIdx.x;   // BB*LL*LL
  int b  = o >> 14;
  int r  = (o >> 7) & (LL - 1);
  int kk = o & (LL - 1);
  bool mask = (enc[b * LL + kk] == 0);
  int md = MD[o];
  float4 m = *(const float4*)(memb + md * 4);
  float mv[4] = {m.x, m.y, m.z, m.w};
#pragma unroll
  for (int h = 0; h < 4; ++h) {
    uint16_t v = mask ? (uint16_t)0xce6eu : f2bf(mv[h]);
    biasT[(((size_t)(b * 4 + h) * LL) + r) * LL + kk] = v;
  }
}

// ---------- LN helper: v[j][ct] over one 16-row tile (wave-local) ----------
DI void ln_write(float (&v)[4][4], float (&xfh)[4][4], uint16_t* __restrict__ xls,
                 int r0, int g, int c) {
  float sum[4], sq[4];
#pragma unroll
  for (int j = 0; j < 4; ++j) sum[j] = (v[j][0] + v[j][1]) + (v[j][2] + v[j][3]);
#pragma unroll
  for (int off = 1; off < 16; off <<= 1)
#pragma unroll
    for (int j = 0; j < 4; ++j) sum[j] += __shfl_xor(sum[j], off, 64);
#pragma unroll
  for (int j = 0; j < 4; ++j) {
    float mu = sum[j] * 0.015625f;
#pragma unroll
    for (int ct = 0; ct < 4; ++ct) v[j][ct] -= mu;
    sq[j] = (v[j][0] * v[j][0] + v[j][1] * v[j][1]) + (v[j][2] * v[j][2] + v[j][3] * v[j][3]);
  }
#pragma unroll
  for (int off = 1; off < 16; off <<= 1)
#pragma unroll
    for (int j = 0; j < 4; ++j) sq[j] += __shfl_xor(sq[j], off, 64);
#pragma unroll
  for (int j = 0; j < 4; ++j) {
    float rstd = rsqrtf(sq[j] * 0.015625f + 1e-5f);
#pragma unroll
    for (int ct = 0; ct < 4; ++ct) {
      float r = v[j][ct] * rstd;
      xfh[ct][j] = r;
      xls[(r0 + g * 4 + j) * 72 + ct * 16 + c] = f2bf(r);
    }
  }
}

// ---------- LDS layout (bytes), 512-thread / 8-wave block (r15 map, ptl stride 272) ----------
// XLS  [128][72] u16 @ 0        (18432)  persistent
// KLS(h) @ 18432 + h*10240  [128][40] (cols 16..31 zero, re-zeroed per layer)
// VTL(h) @ 59392 + h*4352   [16][136]
// QSC(w) @ 76800 + w*1280   [16][40]  (pad cols re-zeroed per layer)
// PTL(w) @ 87040 + w*4352   bias+P tile, 272B rows (g-group bank spread), swizzled
// CTXL   @ 121856 [128][72]  (dedicated, no alias)
// FFN phase: HID(w) @ 18432 + w*8448  [16][264]  (aliases KLS+VTL+QSC, ends 86016 < 87040)
constexpr int LDS_TOTAL = 140288;

// ---------- one attention row-tile (16 rows): T14 bias ping-pong + exp/PV interleave ----------
template<int RT>
DI void attn_rt(bf16x8 (&cur)[4], bf16x8 (&nxt)[4],
                const uint16_t* __restrict__ bb, int hrow0,
                char* ptlb, uint16_t* qsc, const bf16x8 (&kf)[8],
                const uint16_t* vtlh, const uint2 (&qreg)[4], uint2 (&creg)[4],
                int lane, int g, int c) {
  int rl = lane >> 2, seg = lane & 3;
  int swz = (rl & 7) << 4;
  // commit this tile's bias (loaded one iteration ago) into swizzled ptl (272B rows)
  *(bf16x8*)(ptlb + rl * 272 + ((seg * 64 +  0) ^ swz)) = cur[0];
  *(bf16x8*)(ptlb + rl * 272 + ((seg * 64 + 16) ^ swz)) = cur[1];
  *(bf16x8*)(ptlb + rl * 272 + ((seg * 64 + 32) ^ swz)) = cur[2];
  *(bf16x8*)(ptlb + rl * 272 + ((seg * 64 + 48) ^ swz)) = cur[3];
  // prefetch next tile's bias into the other register set (hidden under compute below)
  if (RT < 3) {
    const uint16_t* gs = bb + (size_t)(hrow0 + (RT + 1) * 16 + rl) * LL + seg * 32;
    nxt[0] = *(const bf16x8*)(gs);
    nxt[1] = *(const bf16x8*)(gs + 8);
    nxt[2] = *(const bf16x8*)(gs + 16);
    nxt[3] = *(const bf16x8*)(gs + 24);
  }
  // stage q C-frag -> qsc (pads pre-zeroed)
  qsc[(g * 4 + 0) * 40 + c] = (uint16_t)(qreg[RT].x & 0xffff);
  qsc[(g * 4 + 1) * 40 + c] = (uint16_t)(qreg[RT].x >> 16);
  qsc[(g * 4 + 2) * 40 + c] = (uint16_t)(qreg[RT].y & 0xffff);
  qsc[(g * 4 + 3) * 40 + c] = (uint16_t)(qreg[RT].y >> 16);
  bf16x8 qf = fragld(qsc, 40, lane);
  f32x4 s[8];
#pragma unroll
  for (int ct = 0; ct < 8; ++ct) s[ct] = MFMA(qf, kf[ct], (f32x4){0.f, 0.f, 0.f, 0.f});
  // exp/PV interleaved per 32-col chunk: exp on VALU overlaps PV MFMA of prior chunk
  float rs[4] = {0.f, 0.f, 0.f, 0.f};
  f32x4 o = {0.f, 0.f, 0.f, 0.f};
#pragma unroll
  for (int kc = 0; kc < 4; ++kc) {
#pragma unroll
    for (int cti = 0; cti < 2; ++cti) {
      int ct = kc * 2 + cti;
      int kk = ct * 16 + c;
#pragma unroll
      for (int j = 0; j < 4; ++j) {
        int row = g * 4 + j;
        char* addr = ptlb + row * 272 + ((kk * 2) ^ ((row & 7) << 4));
        float bias = bf2f(*(uint16_t*)addr);
        float p = __expf(fmaf(s[ct][j], 0.25f, bias));
        rs[j] += p;
        *(uint16_t*)addr = f2bf(p);
      }
    }
    bf16x8 vf = fragld(vtlh + kc * 32, 136, lane);
    bf16x8 af = *(const bf16x8*)(ptlb + c * 272 + ((kc * 64 + g * 16) ^ ((c & 7) << 4)));
    o = MFMA(af, vf, o);
  }
#pragma unroll
  for (int off = 1; off < 16; off <<= 1)
#pragma unroll
    for (int j = 0; j < 4; ++j) rs[j] += __shfl_xor(rs[j], off, 64);
  creg[RT].x = pack2(o[0] / rs[0], o[1] / rs[1]);
  creg[RT].y = pack2(o[2] / rs[2], o[3] / rs[3]);
}

// ---------- megakernel: one workgroup (512 thr, 8 waves) per b ----------
__global__ void __launch_bounds__(512, 1) k_mega(
    const float* __restrict__ x0, const uint16_t* __restrict__ xb0,
    const uint16_t* __restrict__ biasT,
    const uint16_t* __restrict__ wtqkv, const uint16_t* __restrict__ wto,
    const uint16_t* __restrict__ wt1, const uint16_t* __restrict__ wt2,
    float* __restrict__ out) {
  __shared__ __align__(16) char LDSB[LDS_TOTAL];
  int tid = threadIdx.x;
  int w8 = tid >> 6, lane = tid & 63;
  int g = lane >> 4, c = lane & 15;
  int h = w8 & 3, half = w8 >> 2;      // attn role: head h, rows half*64..+63
  int b = blockIdx.x;

  uint16_t* xls  = (uint16_t*)(LDSB);
  char*     klsA = LDSB + 18432;
  uint16_t* klsh = (uint16_t*)(LDSB + 18432 + h * 10240);
  uint16_t* vtlh = (uint16_t*)(LDSB + 59392 + h * 4352);
  uint16_t* qsc  = (uint16_t*)(LDSB + 76800 + w8 * 1280);
  char*     ptlb = LDSB + 87040 + w8 * 4352;
  uint16_t* ctxl = (uint16_t*)(LDSB + 121856);
  uint16_t* hidl = (uint16_t*)(LDSB + 18432 + w8 * 8448);

  int r0 = w8 * 16;                    // O-proj/FFN rows
  int hrow0 = half * 64;

  // ---- residual regs: rows r0..r0+15, all 64 cols (C-frag layout) ----
  float xf[4][4];
  const float* xrow = x0 + ((size_t)b * LL + r0) * DM;
#pragma unroll
  for (int ct = 0; ct < 4; ++ct)
#pragma unroll
    for (int j = 0; j < 4; ++j)
      xf[ct][j] = xrow[(g * 4 + j) * DM + ct * 16 + c];
  // ---- xls fill (whole b) ----
  {
    const uint16_t* xbrow = xb0 + (size_t)b * LL * DM;
#pragma unroll
    for (int m = 0; m < 2; ++m) {
      int u = tid * 2 + m;             // 0..1023 units of 8 elems
      int r = u >> 3, col = (u & 7) * 8;
      *(bf16x8*)(xls + r * 72 + col) = *(const bf16x8*)(xbrow + r * DM + col);
    }
  }
  const uint16_t* bb = biasT + ((size_t)b * 4 + h) * (LL * LL);
  __syncthreads();

  for (int li = 0; li < NL; ++li) {
    // ---- re-zero kls + qsc pad cols (clobbered by FFN hid aliasing) ----
#pragma unroll
    for (int m = 0; m < 2; ++m) {
      int idx = tid * 2 + m;           // 0..1023
      int head = idx >> 8, r = (idx >> 1) & 127, s2 = idx & 1;
      *(uint4*)(klsA + head * 10240 + r * 80 + 32 + s2 * 16) = uint4{0, 0, 0, 0};
    }
    if (lane < 32) {
      int r = lane >> 1, s2 = lane & 1;
      *(uint4*)((char*)qsc + r * 80 + 32 + s2 * 16) = uint4{0, 0, 0, 0};
    }

    // ---- QKV: wave (h,half) computes q/k/v of head h for rows hrow0..+63 ----
    const uint16_t* Wl = wtqkv + (size_t)li * 192 * 64;
    bf16x8 bq0 = fragld(Wl + (h * 16) * 64, 64, lane);
    bf16x8 bq1 = fragld(Wl + (h * 16) * 64 + 32, 64, lane);
    bf16x8 bk0 = fragld(Wl + (64 + h * 16) * 64, 64, lane);
    bf16x8 bk1 = fragld(Wl + (64 + h * 16) * 64 + 32, 64, lane);
    bf16x8 bv0 = fragld(Wl + (128 + h * 16) * 64, 64, lane);
    bf16x8 bv1 = fragld(Wl + (128 + h * 16) * 64 + 32, 64, lane);
    uint2 qreg[4];
#pragma unroll
    for (int rt = 0; rt < 4; ++rt) {
      int rr = hrow0 + rt * 16;
      bf16x8 a0 = fragld(xls + rr * 72, 72, lane);
      bf16x8 a1 = fragld(xls + rr * 72 + 32, 72, lane);
      f32x4 aq = {0,0,0,0}, ak = {0,0,0,0}, av = {0,0,0,0};
      aq = MFMA(a0, bq0, aq); aq = MFMA(a1, bq1, aq);
      ak = MFMA(a0, bk0, ak); ak = MFMA(a1, bk1, ak);
      av = MFMA(a0, bv0, av); av = MFMA(a1, bv1, av);
#pragma unroll
      for (int j = 0; j < 4; ++j)
        klsh[(rr + g * 4 + j) * 40 + c] = f2bf(ak[j]);
      uint2 pk; pk.x = pack2(av[0], av[1]); pk.y = pack2(av[2], av[3]);
      *(uint2*)(vtlh + c * 136 + rr + g * 4) = pk;     // V^T [d][kk]
      qreg[rt].x = pack2(aq[0], aq[1]); qreg[rt].y = pack2(aq[2], aq[3]);
    }
    // T14: issue rt0's bias loads now — they complete under the barrier + kf loads + QK^T
    bf16x8 bregA[4], bregB[4];
    {
      int rl = lane >> 2, seg = lane & 3;
      const uint16_t* gs = bb + (size_t)(hrow0 + rl) * LL + seg * 32;
      bregA[0] = *(const bf16x8*)(gs);
      bregA[1] = *(const bf16x8*)(gs + 8);
      bregA[2] = *(const bf16x8*)(gs + 16);
      bregA[3] = *(const bf16x8*)(gs + 24);
    }
    __syncthreads();   // (1) kls/vtl ready

    // ---- attention: head h, Q rows hrow0..+63 ----
    bf16x8 kf[8];
#pragma unroll
    for (int ct = 0; ct < 8; ++ct) kf[ct] = fragld(klsh + ct * 16 * 40, 40, lane);
    uint2 creg[4];
    attn_rt<0>(bregA, bregB, bb, hrow0, ptlb, qsc, kf, vtlh, qreg, creg, lane, g, c);
    attn_rt<1>(bregB, bregA, bb, hrow0, ptlb, qsc, kf, vtlh, qreg, creg, lane, g, c);
    attn_rt<2>(bregA, bregB, bb, hrow0, ptlb, qsc, kf, vtlh, qreg, creg, lane, g, c);
    attn_rt<3>(bregB, bregA, bb, hrow0, ptlb, qsc, kf, vtlh, qreg, creg, lane, g, c);

    // ---- ctx regs -> ctxl (dedicated buffer; no hazard, write immediately) ----
#pragma unroll
    for (int rt = 0; rt < 4; ++rt) {
      int rr = hrow0 + rt * 16;
      ctxl[(rr + g * 4 + 0) * 72 + h * 16 + c] = (uint16_t)(creg[rt].x & 0xffff);
      ctxl[(rr + g * 4 + 1) * 72 + h * 16 + c] = (uint16_t)(creg[rt].x >> 16);
      ctxl[(rr + g * 4 + 2) * 72 + h * 16 + c] = (uint16_t)(creg[rt].y & 0xffff);
      ctxl[(rr + g * 4 + 3) * 72 + h * 16 + c] = (uint16_t)(creg[rt].y >> 16);
    }
    __syncthreads();   // (2) ctxl complete AND all kls/vtl reads done (hid may clobber)

    // ---- O-proj + residual + LN (wave owns rows r0..+15) ----
    {
      const uint16_t* Wol = wto + (size_t)li * 64 * 64;
      bf16x8 a0 = fragld(ctxl + r0 * 72, 72, lane);
      bf16x8 a1 = fragld(ctxl + r0 * 72 + 32, 72, lane);
      float v[4][4];
#pragma unroll
      for (int ct = 0; ct < 4; ++ct) {
        f32x4 acc = {0,0,0,0};
        acc = MFMA(a0, fragld(Wol + ct * 16 * 64, 64, lane), acc);
        acc = MFMA(a1, fragld(Wol + ct * 16 * 64 + 32, 64, lane), acc);
#pragma unroll
        for (int j = 0; j < 4; ++j) v[j][ct] = acc[j] + xf[ct][j];
      }
      ln_write(v, xf, xls, r0, g, c);
    }

    // ---- FFN (wave-local rows; hid [16][264]; FFN1/FFN2 interleaved per 32-col pair) ----
    {
      const uint16_t* W1l = wt1 + (size_t)li * 512 * 64;
      const uint16_t* W2l = wt2 + (size_t)li * 64 * 512;
      bf16x8 a0 = fragld(xls + r0 * 72, 72, lane);
      bf16x8 a1 = fragld(xls + r0 * 72 + 32, 72, lane);
      f32x4 acc2[4] = {{0,0,0,0},{0,0,0,0},{0,0,0,0},{0,0,0,0}};
#pragma unroll
      for (int fh = 0; fh < 2; ++fh) {
#pragma unroll
        for (int pc = 0; pc < 8; ++pc) {   // FIX: 8 pairs = all 16 tiles per fh pass
          // FFN1: write hid tiles 2pc, 2pc+1 of this fh pass
#pragma unroll
          for (int cti = 0; cti < 2; ++cti) {
            int ct2 = pc * 2 + cti;
            int ctg = fh * 16 + ct2;
            f32x4 acc = {0,0,0,0};
            acc = MFMA(a0, fragld(W1l + ctg * 16 * 64, 64, lane), acc);
            acc = MFMA(a1, fragld(W1l + ctg * 16 * 64 + 32, 64, lane), acc);
#pragma unroll
            for (int j = 0; j < 4; ++j)
              hidl[(g * 4 + j) * 264 + ct2 * 16 + c] = f2bf(fmaxf(acc[j], 0.f));
          }
          // FFN2: consume those 32 cols immediately (2-deep dependency instead of 8)
          bf16x8 a = fragld(hidl + pc * 32, 264, lane);
          int kg = fh * 256 + pc * 32;
#pragma unroll
          for (int ct = 0; ct < 4; ++ct)
            acc2[ct] = MFMA(a, fragld(W2l + ct * 16 * 512 + kg, 512, lane), acc2[ct]);
        }
      }
      float v[4][4];
#pragma unroll
      for (int ct = 0; ct < 4; ++ct)
#pragma unroll
        for (int j = 0; j < 4; ++j) v[j][ct] = acc2[ct][j] + xf[ct][j];
      ln_write(v, xf, xls, r0, g, c);
    }
    __syncthreads();   // (3) end of layer: xls updated, hid reads done
  }

  // ---- write f32 output (own rows) ----
  float* orow = out + ((size_t)b * LL + r0) * DM;
#pragma unroll
  for (int ct = 0; ct < 4; ++ct)
#pragma unroll
    for (int j = 0; j < 4; ++j)
      orow[(g * 4 + j) * DM + ct * 16 + c] = xf[ct][j];
}

} // namespace

extern "C" void kernel_launch(void* const* d_in, const int* in_sizes, int n_in,
                              void* d_out, int out_size, void* d_ws, size_t ws_size,
                              hipStream_t stream) {
  const int* enc = (const int*)d_in[0];
  const int* deg = (const int*)d_in[1];
  const int* MD  = (const int*)d_in[2];
  const float* semb = (const float*)d_in[3];
  const float* demb = (const float*)d_in[4];
  const float* memb = (const float*)d_in[5];
  const float* Wq = (const float*)d_in[6];
  const float* Wk = (const float*)d_in[7];
  const float* Wv = (const float*)d_in[8];
  const float* Wo = (const float*)d_in[9];
  const float* W1 = (const float*)d_in[10];
  const float* W2 = (const float*)d_in[11];

  // ---- workspace layout (~47 MB) ----
  char* p = (char*)d_ws;
  float*    x    = (float*)p;     p += (size_t)TT * DM * 4;         // embed output, f32
  uint16_t* xb   = (uint16_t*)p;  p += (size_t)TT * DM * 2;         // bf16 shadow
  uint16_t* biasT = (uint16_t*)p; p += (size_t)BB * 4 * LL * LL * 2; // [b][h][r][kk]
  uint16_t* wtqkv = (uint16_t*)p; p += (size_t)NL * 192 * 64 * 2;   // [l][c:192][k:64]
  uint16_t* wto   = (uint16_t*)p; p += (size_t)NL * 64 * 64 * 2;    // [l][c:64][k:64]
  uint16_t* wt1   = (uint16_t*)p; p += (size_t)NL * 512 * 64 * 2;   // [l][c:512][k:64]
  uint16_t* wt2   = (uint16_t*)p; p += (size_t)NL * 64 * 512 * 2;   // [l][c:64][k:512]
  (void)ws_size; (void)in_sizes; (void)n_in; (void)out_size;

  // ---- setup ----
  k_embed<<<TT * DM / 256, 256, 0, stream>>>(enc, deg, semb, demb, x, xb);
  k_trans<<<NL * 64 * 64 / 256, 256, 0, stream>>>(Wq, wtqkv, 64, 64, 192 * 64, 0);
  k_trans<<<NL * 64 * 64 / 256, 256, 0, stream>>>(Wk, wtqkv, 64, 64, 192 * 64, 64);
  k_trans<<<NL * 64 * 64 / 256, 256, 0, stream>>>(Wv, wtqkv, 64, 64, 192 * 64, 128);
  k_trans<<<NL * 64 * 64 / 256, 256, 0, stream>>>(Wo, wto, 64, 64, 64 * 64, 0);
  k_trans<<<NL * 64 * 512 / 256, 256, 0, stream>>>(W1, wt1, 64, 512, 512 * 64, 0);
  k_trans<<<NL * 512 * 64 / 256, 256, 0, stream>>>(W2, wt2, 512, 64, 64 * 512, 0);
  k_bias2<<<BB * LL * LL / 256, 256, 0, stream>>>(MD, memb, enc, biasT);

  // ---- whole network: one 8-wave workgroup per batch element ----
  k_mega<<<BB, 512, 0, stream>>>(x, xb, biasT, wtqkv, wto, wt1, wt2, (float*)d_out);
}

// Round 20
// 303.342 us; speedup vs baseline: 1.0925x; 1.0925x over previous
//
#include <hip/hip_runtime.h>
#include <hip/hip_bf16.h>
#include <stdint.h>

#define DI __device__ __forceinline__

namespace {

constexpr int BB  = 256;   // batch
constexpr int LL  = 128;   // seq len
constexpr int DM  = 64;    // d_model
constexpr int DFF = 512;   // ffn dim
constexpr int NL  = 6;     // layers
constexpr int TT  = BB * LL;  // 32768 tokens

typedef __attribute__((ext_vector_type(8))) short bf16x8;   // MFMA A/B frag (4 VGPR)
typedef __attribute__((ext_vector_type(4))) float f32x4;    // MFMA C/D frag

// ---------- bf16 helpers ----------
DI float bf2f(uint16_t u) { union { uint32_t i; float f; } w; w.i = (uint32_t)u << 16; return w.f; }
DI uint16_t f2bf(float f) {
  union { float f; uint32_t i; } w; w.f = f;
  uint32_t r = (w.i + 0x7fffu + ((w.i >> 16) & 1u)) >> 16;  // RNE
  return (uint16_t)r;
}
DI uint32_t pack2(float a, float b) { return (uint32_t)f2bf(a) | ((uint32_t)f2bf(b) << 16); }

// fragment load: lane l reads 8 bf16 at row (l&15), k-offset (l>>4)*8 of a row-major [16 x ld] tile
DI bf16x8 fragld(const uint16_t* __restrict__ base, int ld, int lane) {
  return *(const bf16x8*)(base + (size_t)(lane & 15) * ld + (lane >> 4) * 8);
}
DI f32x4 MFMA(bf16x8 a, bf16x8 b, f32x4 c) {
  return __builtin_amdgcn_mfma_f32_16x16x32_bf16(a, b, c, 0, 0, 0);
}

// ---------- setup kernels ----------
__global__ void __launch_bounds__(256) k_embed(const int* __restrict__ enc, const int* __restrict__ deg,
    const float* __restrict__ semb, const float* __restrict__ demb,
    float* __restrict__ x, uint16_t* __restrict__ xb) {
  int idx = blockIdx.x * 256 + threadIdx.x;   // T*64
  int t = idx >> 6, d = idx & 63;
  int l = t & (LL - 1);
  float e = (float)(d & ~1) * -0.14391156831212787f;   // -ln(10000)/64
  float ang = (float)l * __expf(e);
  float pe = (d & 1) ? __cosf(ang) : __sinf(ang);
  float v = semb[enc[t] * DM + d] + demb[deg[t] * DM + d] + pe;
  x[idx] = v;
  xb[idx] = f2bf(v);
}

__global__ void __launch_bounds__(256) k_trans(const float* __restrict__ w, uint16_t* __restrict__ wt,
    int K, int O, int dstStride, int colOff) {
  int idx = blockIdx.x * 256 + threadIdx.x;   // nmat*K*O
  int KO = K * O;
  int mat = idx / KO;
  int rem = idx - mat * KO;
  int c = rem / K;
  int k = rem - c * K;
  wt[(size_t)mat * dstStride + (size_t)(colOff + c) * K + k] = f2bf(w[((size_t)mat * K + k) * O + c]);
}

// biasT[b][h][r][kk] bf16 = mask(kk) ? -1e9 : md_emb[MD[b,r,kk]][h]   (layer-invariant)
__global__ void __launch_bounds__(256) k_bias2(const int* __restrict__ MD, const float* __restrict__ memb,
    const int* __restrict__ enc, uint16_t* __restrict__ biasT) {
  int o = blockIdx.x * 256 + threadIdx.x;   // BB*LL*LL
  int b  = o >> 14;
  int r  = (o >> 7) & (LL - 1);
  int kk = o & (LL - 1);
  bool mask = (enc[b * LL + kk] == 0);
  int md = MD[o];
  float4 m = *(const float4*)(memb + md * 4);
  float mv[4] = {m.x, m.y, m.z, m.w};
#pragma unroll
  for (int h = 0; h < 4; ++h) {
    uint16_t v = mask ? (uint16_t)0xce6eu : f2bf(mv[h]);
    biasT[(((size_t)(b * 4 + h) * LL) + r) * LL + kk] = v;
  }
}

// ---------- LN helper: v[j][ct] over one 16-row tile (wave-local) ----------
DI void ln_write(float (&v)[4][4], float (&xfh)[4][4], uint16_t* __restrict__ xls,
                 int r0, int g, int c) {
  float sum[4], sq[4];
#pragma unroll
  for (int j = 0; j < 4; ++j) sum[j] = (v[j][0] + v[j][1]) + (v[j][2] + v[j][3]);
#pragma unroll
  for (int off = 1; off < 16; off <<= 1)
#pragma unroll
    for (int j = 0; j < 4; ++j) sum[j] += __shfl_xor(sum[j], off, 64);
#pragma unroll
  for (int j = 0; j < 4; ++j) {
    float mu = sum[j] * 0.015625f;
#pragma unroll
    for (int ct = 0; ct < 4; ++ct) v[j][ct] -= mu;
    sq[j] = (v[j][0] * v[j][0] + v[j][1] * v[j][1]) + (v[j][2] * v[j][2] + v[j][3] * v[j][3]);
  }
#pragma unroll
  for (int off = 1; off < 16; off <<= 1)
#pragma unroll
    for (int j = 0; j < 4; ++j) sq[j] += __shfl_xor(sq[j], off, 64);
#pragma unroll
  for (int j = 0; j < 4; ++j) {
    float rstd = rsqrtf(sq[j] * 0.015625f + 1e-5f);
#pragma unroll
    for (int ct = 0; ct < 4; ++ct) {
      float r = v[j][ct] * rstd;
      xfh[ct][j] = r;
      xls[(r0 + g * 4 + j) * 72 + ct * 16 + c] = f2bf(r);
    }
  }
}

// ---------- LDS layout (bytes), 512-thread / 8-wave block ----------
// XLS  [128][72] u16 @ 0        (18432)  persistent
// KLS(h) @ 18432 + h*10240  [128][40] (cols 16..31 zero, re-zeroed per layer)
// VTL(h) @ 59392 + h*4352   [16][136]
// QSC(w) @ 76800 + w*1280   [16][40]  (pad cols re-zeroed per layer)
// PTL(w) @ 87040 + w*4096   bias+P tile, swizzled 256B rows (row*256 is bank-neutral;
//                            XOR (row&7)<<4 alone gives the conflict-free spread — do NOT pad stride)
// CTXL   @ 119808 [128][72]  (dedicated, no alias)
// FFN phase: HID(w) @ 18432 + w*8448  [16][264]  (aliases KLS+VTL+QSC, ends 86016 < 87040)
constexpr int LDS_TOTAL = 138240;

// ---------- one attention row-tile (16 rows), with T14 bias ping-pong ----------
template<int RT>
DI void attn_rt(bf16x8 (&cur)[4], bf16x8 (&nxt)[4],
                const uint16_t* __restrict__ bb, int hrow0,
                char* ptlb, uint16_t* qsc, const bf16x8 (&kf)[8],
                const uint16_t* vtlh, const uint2 (&qreg)[4], uint2 (&creg)[4],
                int lane, int g, int c) {
  int rl = lane >> 2, seg = lane & 3;
  int swz = (rl & 7) << 4;
  // commit this tile's bias (loaded one iteration ago) into swizzled ptl
  *(bf16x8*)(ptlb + rl * 256 + ((seg * 64 +  0) ^ swz)) = cur[0];
  *(bf16x8*)(ptlb + rl * 256 + ((seg * 64 + 16) ^ swz)) = cur[1];
  *(bf16x8*)(ptlb + rl * 256 + ((seg * 64 + 32) ^ swz)) = cur[2];
  *(bf16x8*)(ptlb + rl * 256 + ((seg * 64 + 48) ^ swz)) = cur[3];
  // prefetch next tile's bias into the other register set (hidden under compute below)
  if (RT < 3) {
    const uint16_t* gs = bb + (size_t)(hrow0 + (RT + 1) * 16 + rl) * LL + seg * 32;
    nxt[0] = *(const bf16x8*)(gs);
    nxt[1] = *(const bf16x8*)(gs + 8);
    nxt[2] = *(const bf16x8*)(gs + 16);
    nxt[3] = *(const bf16x8*)(gs + 24);
  }
  // stage q C-frag -> qsc (dedicated, pads pre-zeroed)
  qsc[(g * 4 + 0) * 40 + c] = (uint16_t)(qreg[RT].x & 0xffff);
  qsc[(g * 4 + 1) * 40 + c] = (uint16_t)(qreg[RT].x >> 16);
  qsc[(g * 4 + 2) * 40 + c] = (uint16_t)(qreg[RT].y & 0xffff);
  qsc[(g * 4 + 3) * 40 + c] = (uint16_t)(qreg[RT].y >> 16);
  bf16x8 qf = fragld(qsc, 40, lane);
  f32x4 s[8];
#pragma unroll
  for (int ct = 0; ct < 8; ++ct) s[ct] = MFMA(qf, kf[ct], (f32x4){0.f, 0.f, 0.f, 0.f});
  float rs[4] = {0.f, 0.f, 0.f, 0.f};
#pragma unroll
  for (int ct = 0; ct < 8; ++ct) {
    int kk = ct * 16 + c;
#pragma unroll
    for (int j = 0; j < 4; ++j) {
      int row = g * 4 + j;
      char* addr = ptlb + row * 256 + ((kk * 2) ^ ((row & 7) << 4));
      float bias = bf2f(*(uint16_t*)addr);
      float p = __expf(fmaf(s[ct][j], 0.25f, bias));
      rs[j] += p;
      *(uint16_t*)addr = f2bf(p);
    }
  }
#pragma unroll
  for (int off = 1; off < 16; off <<= 1)
#pragma unroll
    for (int j = 0; j < 4; ++j) rs[j] += __shfl_xor(rs[j], off, 64);
  bf16x8 vf[4];
#pragma unroll
  for (int kc = 0; kc < 4; ++kc) vf[kc] = fragld(vtlh + kc * 32, 136, lane);
  f32x4 o = {0.f, 0.f, 0.f, 0.f};
#pragma unroll
  for (int kc = 0; kc < 4; ++kc) {
    bf16x8 af = *(const bf16x8*)(ptlb + c * 256 + ((kc * 64 + g * 16) ^ ((c & 7) << 4)));
    o = MFMA(af, vf[kc], o);
  }
  creg[RT].x = pack2(o[0] / rs[0], o[1] / rs[1]);
  creg[RT].y = pack2(o[2] / rs[2], o[3] / rs[3]);
}

// ---------- megakernel: one workgroup (512 thr, 8 waves) per b ----------
__global__ void __launch_bounds__(512, 1) k_mega(
    const float* __restrict__ x0, const uint16_t* __restrict__ xb0,
    const uint16_t* __restrict__ biasT,
    const uint16_t* __restrict__ wtqkv, const uint16_t* __restrict__ wto,
    const uint16_t* __restrict__ wt1, const uint16_t* __restrict__ wt2,
    float* __restrict__ out) {
  __shared__ __align__(16) char LDSB[LDS_TOTAL];
  int tid = threadIdx.x;
  int w8 = tid >> 6, lane = tid & 63;
  int g = lane >> 4, c = lane & 15;
  int h = w8 & 3, half = w8 >> 2;      // attn role: head h, rows half*64..+63
  int b = blockIdx.x;

  uint16_t* xls  = (uint16_t*)(LDSB);
  char*     klsA = LDSB + 18432;
  uint16_t* klsh = (uint16_t*)(LDSB + 18432 + h * 10240);
  uint16_t* vtlh = (uint16_t*)(LDSB + 59392 + h * 4352);
  uint16_t* qsc  = (uint16_t*)(LDSB + 76800 + w8 * 1280);
  char*     ptlb = LDSB + 87040 + w8 * 4096;
  uint16_t* ctxl = (uint16_t*)(LDSB + 119808);
  uint16_t* hidl = (uint16_t*)(LDSB + 18432 + w8 * 8448);

  int r0 = w8 * 16;                    // O-proj/FFN rows
  int hrow0 = half * 64;

  // ---- residual regs: rows r0..r0+15, all 64 cols (C-frag layout) ----
  float xf[4][4];
  const float* xrow = x0 + ((size_t)b * LL + r0) * DM;
#pragma unroll
  for (int ct = 0; ct < 4; ++ct)
#pragma unroll
    for (int j = 0; j < 4; ++j)
      xf[ct][j] = xrow[(g * 4 + j) * DM + ct * 16 + c];
  // ---- xls fill (whole b) ----
  {
    const uint16_t* xbrow = xb0 + (size_t)b * LL * DM;
#pragma unroll
    for (int m = 0; m < 2; ++m) {
      int u = tid * 2 + m;             // 0..1023 units of 8 elems
      int r = u >> 3, col = (u & 7) * 8;
      *(bf16x8*)(xls + r * 72 + col) = *(const bf16x8*)(xbrow + r * DM + col);
    }
  }
  const uint16_t* bb = biasT + ((size_t)b * 4 + h) * (LL * LL);
  __syncthreads();

  for (int li = 0; li < NL; ++li) {
    // ---- re-zero kls + qsc pad cols (clobbered by FFN hid aliasing) ----
#pragma unroll
    for (int m = 0; m < 2; ++m) {
      int idx = tid * 2 + m;           // 0..1023
      int head = idx >> 8, r = (idx >> 1) & 127, s2 = idx & 1;
      *(uint4*)(klsA + head * 10240 + r * 80 + 32 + s2 * 16) = uint4{0, 0, 0, 0};
    }
    if (lane < 32) {
      int r = lane >> 1, s2 = lane & 1;
      *(uint4*)((char*)qsc + r * 80 + 32 + s2 * 16) = uint4{0, 0, 0, 0};
    }

    // ---- QKV: wave (h,half) computes q/k/v of head h for rows hrow0..+63 ----
    const uint16_t* Wl = wtqkv + (size_t)li * 192 * 64;
    bf16x8 bq0 = fragld(Wl + (h * 16) * 64, 64, lane);
    bf16x8 bq1 = fragld(Wl + (h * 16) * 64 + 32, 64, lane);
    bf16x8 bk0 = fragld(Wl + (64 + h * 16) * 64, 64, lane);
    bf16x8 bk1 = fragld(Wl + (64 + h * 16) * 64 + 32, 64, lane);
    bf16x8 bv0 = fragld(Wl + (128 + h * 16) * 64, 64, lane);
    bf16x8 bv1 = fragld(Wl + (128 + h * 16) * 64 + 32, 64, lane);
    uint2 qreg[4];
#pragma unroll
    for (int rt = 0; rt < 4; ++rt) {
      int rr = hrow0 + rt * 16;
      bf16x8 a0 = fragld(xls + rr * 72, 72, lane);
      bf16x8 a1 = fragld(xls + rr * 72 + 32, 72, lane);
      f32x4 aq = {0,0,0,0}, ak = {0,0,0,0}, av = {0,0,0,0};
      aq = MFMA(a0, bq0, aq); aq = MFMA(a1, bq1, aq);
      ak = MFMA(a0, bk0, ak); ak = MFMA(a1, bk1, ak);
      av = MFMA(a0, bv0, av); av = MFMA(a1, bv1, av);
#pragma unroll
      for (int j = 0; j < 4; ++j)
        klsh[(rr + g * 4 + j) * 40 + c] = f2bf(ak[j]);
      uint2 pk; pk.x = pack2(av[0], av[1]); pk.y = pack2(av[2], av[3]);
      *(uint2*)(vtlh + c * 136 + rr + g * 4) = pk;     // V^T [d][kk]
      qreg[rt].x = pack2(aq[0], aq[1]); qreg[rt].y = pack2(aq[2], aq[3]);
    }
    // T14: issue rt0's bias loads now — they complete under the barrier + kf loads + QK^T
    bf16x8 bregA[4], bregB[4];
    {
      int rl = lane >> 2, seg = lane & 3;
      const uint16_t* gs = bb + (size_t)(hrow0 + rl) * LL + seg * 32;
      bregA[0] = *(const bf16x8*)(gs);
      bregA[1] = *(const bf16x8*)(gs + 8);
      bregA[2] = *(const bf16x8*)(gs + 16);
      bregA[3] = *(const bf16x8*)(gs + 24);
    }
    __syncthreads();   // (1) kls/vtl ready

    // ---- attention: head h, Q rows hrow0..+63 ----
    bf16x8 kf[8];
#pragma unroll
    for (int ct = 0; ct < 8; ++ct) kf[ct] = fragld(klsh + ct * 16 * 40, 40, lane);
    uint2 creg[4];
    attn_rt<0>(bregA, bregB, bb, hrow0, ptlb, qsc, kf, vtlh, qreg, creg, lane, g, c);
    attn_rt<1>(bregB, bregA, bb, hrow0, ptlb, qsc, kf, vtlh, qreg, creg, lane, g, c);
    attn_rt<2>(bregA, bregB, bb, hrow0, ptlb, qsc, kf, vtlh, qreg, creg, lane, g, c);
    attn_rt<3>(bregB, bregA, bb, hrow0, ptlb, qsc, kf, vtlh, qreg, creg, lane, g, c);

    // ---- ctx regs -> ctxl (dedicated buffer; no hazard, write immediately) ----
#pragma unroll
    for (int rt = 0; rt < 4; ++rt) {
      int rr = hrow0 + rt * 16;
      ctxl[(rr + g * 4 + 0) * 72 + h * 16 + c] = (uint16_t)(creg[rt].x & 0xffff);
      ctxl[(rr + g * 4 + 1) * 72 + h * 16 + c] = (uint16_t)(creg[rt].x >> 16);
      ctxl[(rr + g * 4 + 2) * 72 + h * 16 + c] = (uint16_t)(creg[rt].y & 0xffff);
      ctxl[(rr + g * 4 + 3) * 72 + h * 16 + c] = (uint16_t)(creg[rt].y >> 16);
    }
    __syncthreads();   // (2) ctxl complete AND all kls/vtl reads done (hid may clobber)

    // ---- O-proj + residual + LN (wave owns rows r0..+15) ----
    {
      const uint16_t* Wol = wto + (size_t)li * 64 * 64;
      bf16x8 a0 = fragld(ctxl + r0 * 72, 72, lane);
      bf16x8 a1 = fragld(ctxl + r0 * 72 + 32, 72, lane);
      float v[4][4];
#pragma unroll
      for (int ct = 0; ct < 4; ++ct) {
        f32x4 acc = {0,0,0,0};
        acc = MFMA(a0, fragld(Wol + ct * 16 * 64, 64, lane), acc);
        acc = MFMA(a1, fragld(Wol + ct * 16 * 64 + 32, 64, lane), acc);
#pragma unroll
        for (int j = 0; j < 4; ++j) v[j][ct] = acc[j] + xf[ct][j];
      }
      ln_write(v, xf, xls, r0, g, c);
    }

    // ---- FFN (wave-local rows; hid [16][264] in alias region) ----
    {
      const uint16_t* W1l = wt1 + (size_t)li * 512 * 64;
      const uint16_t* W2l = wt2 + (size_t)li * 64 * 512;
      bf16x8 a0 = fragld(xls + r0 * 72, 72, lane);
      bf16x8 a1 = fragld(xls + r0 * 72 + 32, 72, lane);
      f32x4 acc2[4] = {{0,0,0,0},{0,0,0,0},{0,0,0,0},{0,0,0,0}};
#pragma unroll
      for (int fh = 0; fh < 2; ++fh) {
#pragma unroll 4
        for (int ct2 = 0; ct2 < 16; ++ct2) {
          int ctg = fh * 16 + ct2;
          f32x4 acc = {0,0,0,0};
          acc = MFMA(a0, fragld(W1l + ctg * 16 * 64, 64, lane), acc);
          acc = MFMA(a1, fragld(W1l + ctg * 16 * 64 + 32, 64, lane), acc);
#pragma unroll
          for (int j = 0; j < 4; ++j)
            hidl[(g * 4 + j) * 264 + ct2 * 16 + c] = f2bf(fmaxf(acc[j], 0.f));
        }
#pragma unroll 4
        for (int kc2 = 0; kc2 < 8; ++kc2) {
          bf16x8 a = fragld(hidl + kc2 * 32, 264, lane);
          int kg = fh * 256 + kc2 * 32;
#pragma unroll
          for (int ct = 0; ct < 4; ++ct)
            acc2[ct] = MFMA(a, fragld(W2l + ct * 16 * 512 + kg, 512, lane), acc2[ct]);
        }
      }
      float v[4][4];
#pragma unroll
      for (int ct = 0; ct < 4; ++ct)
#pragma unroll
        for (int j = 0; j < 4; ++j) v[j][ct] = acc2[ct][j] + xf[ct][j];
      ln_write(v, xf, xls, r0, g, c);
    }
    __syncthreads();   // (3) end of layer: xls updated, hid reads done
  }

  // ---- write f32 output (own rows) ----
  float* orow = out + ((size_t)b * LL + r0) * DM;
#pragma unroll
  for (int ct = 0; ct < 4; ++ct)
#pragma unroll
    for (int j = 0; j < 4; ++j)
      orow[(g * 4 + j) * DM + ct * 16 + c] = xf[ct][j];
}

} // namespace

extern "C" void kernel_launch(void* const* d_in, const int* in_sizes, int n_in,
                              void* d_out, int out_size, void* d_ws, size_t ws_size,
                              hipStream_t stream) {
  const int* enc = (const int*)d_in[0];
  const int* deg = (const int*)d_in[1];
  const int* MD  = (const int*)d_in[2];
  const float* semb = (const float*)d_in[3];
  const float* demb = (const float*)d_in[4];
  const float* memb = (const float*)d_in[5];
  const float* Wq = (const float*)d_in[6];
  const float* Wk = (const float*)d_in[7];
  const float* Wv = (const float*)d_in[8];
  const float* Wo = (const float*)d_in[9];
  const float* W1 = (const float*)d_in[10];
  const float* W2 = (const float*)d_in[11];

  // ---- workspace layout (~47 MB) ----
  char* p = (char*)d_ws;
  float*    x    = (float*)p;     p += (size_t)TT * DM * 4;         // embed output, f32
  uint16_t* xb   = (uint16_t*)p;  p += (size_t)TT * DM * 2;         // bf16 shadow
  uint16_t* biasT = (uint16_t*)p; p += (size_t)BB * 4 * LL * LL * 2; // [b][h][r][kk]
  uint16_t* wtqkv = (uint16_t*)p; p += (size_t)NL * 192 * 64 * 2;   // [l][c:192][k:64]
  uint16_t* wto   = (uint16_t*)p; p += (size_t)NL * 64 * 64 * 2;    // [l][c:64][k:64]
  uint16_t* wt1   = (uint16_t*)p; p += (size_t)NL * 512 * 64 * 2;   // [l][c:512][k:64]
  uint16_t* wt2   = (uint16_t*)p; p += (size_t)NL * 64 * 512 * 2;   // [l][c:64][k:512]
  (void)ws_size; (void)in_sizes; (void)n_in; (void)out_size;

  // ---- setup ----
  k_embed<<<TT * DM / 256, 256, 0, stream>>>(enc, deg, semb, demb, x, xb);
  k_trans<<<NL * 64 * 64 / 256, 256, 0, stream>>>(Wq, wtqkv, 64, 64, 192 * 64, 0);
  k_trans<<<NL * 64 * 64 / 256, 256, 0, stream>>>(Wk, wtqkv, 64, 64, 192 * 64, 64);
  k_trans<<<NL * 64 * 64 / 256, 256, 0, stream>>>(Wv, wtqkv, 64, 64, 192 * 64, 128);
  k_trans<<<NL * 64 * 64 / 256, 256, 0, stream>>>(Wo, wto, 64, 64, 64 * 64, 0);
  k_trans<<<NL * 64 * 512 / 256, 256, 0, stream>>>(W1, wt1, 64, 512, 512 * 64, 0);
  k_trans<<<NL * 512 * 64 / 256, 256, 0, stream>>>(W2, wt2, 512, 64, 64 * 512, 0);
  k_bias2<<<BB * LL * LL / 256, 256, 0, stream>>>(MD, memb, enc, biasT);

  // ---- whole network: one 8-wave workgroup per batch element ----
  k_mega<<<BB, 512, 0, stream>>>(x, xb, biasT, wtqkv, wto, wt1, wt2, (float*)d_out);
}